// Round 6
// baseline (264.113 us; speedup 1.0000x reference)
//
#include <hip/hip_runtime.h>

#define DCH 1024
#define MSLOT 64
#define NTOK 16384

typedef __bf16 bf16x8 __attribute__((ext_vector_type(8)));
typedef float f32x4 __attribute__((ext_vector_type(4)));
typedef unsigned short u16x8 __attribute__((ext_vector_type(8)));
typedef unsigned short u16x4 __attribute__((ext_vector_type(4)));

__device__ __forceinline__ unsigned short f2bf(float f) {
  unsigned u = __float_as_uint(f);
  u += 0x7fffu + ((u >> 16) & 1u);
  return (unsigned short)(u >> 16);
}
__device__ __forceinline__ float bf2f(unsigned short s) {
  return __uint_as_float(((unsigned)s) << 16);
}

__device__ __forceinline__ void gld16(const void* g, void* l) {
  __builtin_amdgcn_global_load_lds((const __attribute__((address_space(1))) void*)g,
                                   (__attribute__((address_space(3))) void*)l, 16, 0, 0);
}

// ---------------------------------------------------------------------------
// prep_a: fused big conversion pass.
//   b in [0,2048)     : x (f32) -> xb (bf16), grid-stride, 8 float4/thread in
//                       batches of 4 independent loads (fixes R5's dispatch-
//                       rate bound: 1-op blocks at 0.4us lifetime capped
//                       concurrency at 38% occupancy / 1.7 TB/s)
//   b in [2048,2304)  : Wf2 transpose -> Wf2T[c][d] (fp32), 64x64 LDS tiles
//   b in [2304,2368)  : Wf1 -> bf16
//   b == 2368         : sc[m] = bq . memory[m]
// ---------------------------------------------------------------------------
__global__ __launch_bounds__(256) void prep_a_kernel(
    const float* __restrict__ x, unsigned short* __restrict__ xb,
    const float* __restrict__ Wf, float* __restrict__ Wf2T,
    unsigned short* __restrict__ Wf1b,
    const float* __restrict__ bq, const float* __restrict__ memv,
    float* __restrict__ sc) {
  __shared__ float tile[64][65];
  __shared__ float red[256];
  const int b = blockIdx.x, tid = threadIdx.x;

  if (b < 2048) {
    const int base = b * 256 + tid;        // float4 index, [0, 524288)
    const int stride = 2048 * 256;         // float4s per sweep
#pragma unroll
    for (int half = 0; half < 2; ++half) {
      float4 v[4];
#pragma unroll
      for (int j = 0; j < 4; ++j)
        v[j] = *(const float4*)(x + (size_t)(base + (half * 4 + j) * stride) * 4);
#pragma unroll
      for (int j = 0; j < 4; ++j) {
        u16x4 o = {f2bf(v[j].x), f2bf(v[j].y), f2bf(v[j].z), f2bf(v[j].w)};
        *(u16x4*)(xb + (size_t)(base + (half * 4 + j) * stride) * 4) = o;
      }
    }
  } else if (b < 2304) {
    // transpose Wf2: Wf2T[c][d] = Wf[d][1024+c]
    const int t = b - 2048;
    const int c0 = (t & 15) * 64, d0 = (t >> 4) * 64;
    const int lane = tid & 63, wv = tid >> 6;
#pragma unroll
    for (int i = 0; i < 16; ++i) {
      int r = wv + i * 4;   // row within tile
      tile[r][lane] = Wf[(size_t)(d0 + r) * 2048 + 1024 + c0 + lane];
    }
    __syncthreads();
#pragma unroll
    for (int i = 0; i < 16; ++i) {
      int r = wv + i * 4;
      Wf2T[(size_t)(c0 + r) * 1024 + d0 + lane] = tile[lane][r];
    }
  } else if (b < 2368) {
    const int j = b - 2304;   // Wf1 -> bf16, 64 blocks, 4096 float4 each
#pragma unroll
    for (int i = 0; i < 16; ++i) {
      int f4 = j * 4096 + i * 256 + tid;
      int row = f4 >> 8, c4 = (f4 & 255) * 4;
      float4 v = *(const float4*)(Wf + (size_t)row * 2048 + c4);
      u16x4 o = {f2bf(v.x), f2bf(v.y), f2bf(v.z), f2bf(v.w)};
      *(u16x4*)(Wf1b + row * 1024 + c4) = o;
    }
  } else {
    // sc[m] = sum_e bq[e] * memory[m][e]
    int m = tid >> 2, q = tid & 3;
    float s = 0.f;
    for (int e = q * 256; e < q * 256 + 256; ++e) s += bq[e] * memv[m * 1024 + e];
    red[tid] = s;
    __syncthreads();
    if (tid < 64) sc[tid] = red[tid * 4] + red[tid * 4 + 1] + red[tid * 4 + 2] + red[tid * 4 + 3];
  }
}

// ---------------------------------------------------------------------------
// prep_b: split-K partial GEMMs (M=64, N=1024, K=1024, fp32 VALU).
// ---------------------------------------------------------------------------
__global__ __launch_bounds__(256) void prep_b_kernel(
    const float* __restrict__ memv, const float* __restrict__ Wq,
    const float* __restrict__ Wf2T,
    float* __restrict__ partWm, float* __restrict__ partP) {
  int b = blockIdx.x;
  const int tid = threadIdx.x;
  const int which = b >> 7;
  b &= 127;
  const int kc = b & 7, dt = (b >> 3) & 3, mg = b >> 5;
  const float* B = which ? Wf2T : Wq;
  float* outp = which ? partP : partWm;
  const int d = dt * 256 + tid;
  const int e0 = kc * 128;
  const int m0 = mg * 16;

  float acc[16];
#pragma unroll
  for (int m = 0; m < 16; ++m) acc[m] = 0.f;

  const float* bp = B + (size_t)e0 * 1024 + d;
  const float* mp = memv + m0 * 1024 + e0;
#pragma unroll 4
  for (int e = 0; e < 128; ++e) {
    float wv = bp[(size_t)e * 1024];
#pragma unroll
    for (int m = 0; m < 16; ++m) acc[m] += mp[m * 1024 + e] * wv;
  }
  float* op = outp + ((size_t)kc * 64 + m0) * 1024 + d;
#pragma unroll
  for (int m = 0; m < 16; ++m) op[m * 1024] = acc[m];
}

// ---------------------------------------------------------------------------
// prep_c: reduce 8 partials. idx < 65536 -> Wmb (bf16); else -> P (fp32)
// ---------------------------------------------------------------------------
__global__ __launch_bounds__(256) void prep_c_kernel(
    const float* __restrict__ partWm, const float* __restrict__ partP,
    unsigned short* __restrict__ Wmb, float* __restrict__ P) {
  int idx = blockIdx.x * 256 + threadIdx.x;
  if (idx < 65536) {
    float s = 0.f;
#pragma unroll
    for (int k = 0; k < 8; ++k) s += partWm[k * 65536 + idx];
    Wmb[idx] = f2bf(s);
  } else {
    idx -= 65536;
    float s = 0.f;
#pragma unroll
    for (int k = 0; k < 8; ++k) s += partP[k * 65536 + idx];
    P[idx] = s;
  }
}

// ---------------------------------------------------------------------------
// sim_topk: sim = xb @ Wmb^T + sc  (64 tok x 64 m per block), then per-token
// top-3 + softmax -> meta.  XOR-swizzled LDS (see gemm_h comment).
// grid: 256 blocks x 256
// ---------------------------------------------------------------------------
__global__ __launch_bounds__(256) void sim_topk_kernel(
    const unsigned short* __restrict__ xb, const unsigned short* __restrict__ Wmb,
    const float* __restrict__ sc, float4* __restrict__ meta) {
  __shared__ __attribute__((aligned(16))) unsigned short As[64 * 64];
  __shared__ __attribute__((aligned(16))) unsigned short Bs[64 * 64];
  __shared__ float sim_s[64 * 65];
  const int tid = threadIdx.x;
  const int wave = tid >> 6, lane = tid & 63;
  const int tok0 = blockIdx.x * 64;
  const int quad = lane >> 4, cl = lane & 15;
  const int sw = ((lane & 7) ^ (lane >> 3)) * 8;    // staging swizzle (shorts)
  const int cx0 = ((quad) ^ (cl & 7)) * 8;          // read swizzle ks=0
  const int cx1 = ((quad + 4) ^ (cl & 7)) * 8;      // read swizzle ks=1

  f32x4 acc[4];
#pragma unroll
  for (int j = 0; j < 4; ++j) acc[j] = {0.f, 0.f, 0.f, 0.f};

  for (int kt = 0; kt < 16; ++kt) {
    __syncthreads();
#pragma unroll
    for (int i = 0; i < 2; ++i) {
      int ch = (wave * 2 + i) * 64 + lane;
      int row = ch >> 3;
      gld16(xb + (size_t)(tok0 + row) * 1024 + kt * 64 + sw, As + ch * 8);
      gld16(Wmb + row * 1024 + kt * 64 + sw, Bs + ch * 8);
    }
    __syncthreads();
#pragma unroll
    for (int ks = 0; ks < 2; ++ks) {
      const int cx = ks ? cx1 : cx0;
      bf16x8 a = *(const bf16x8*)(As + (wave * 16 + cl) * 64 + cx);
#pragma unroll
      for (int nt = 0; nt < 4; ++nt) {
        bf16x8 bb = *(const bf16x8*)(Bs + (cl + nt * 16) * 64 + cx);
        acc[nt] = __builtin_amdgcn_mfma_f32_16x16x32_bf16(a, bb, acc[nt], 0, 0, 0);
      }
    }
  }
#pragma unroll
  for (int nt = 0; nt < 4; ++nt)
#pragma unroll
    for (int r = 0; r < 4; ++r) {
      int lt = wave * 16 + quad * 4 + r;
      int mc = nt * 16 + cl;
      sim_s[lt * 65 + mc] = acc[nt][r] + sc[mc];
    }
  __syncthreads();
  if (tid < 64) {
    const float* sp = sim_s + tid * 65;
    float s0 = -1e30f, s1 = -1e30f, s2 = -1e30f;
    int i0 = 0, i1 = 0, i2 = 0;
    for (int m = 0; m < 64; ++m) {
      float v = sp[m];
      if (v > s0) { s2 = s1; i2 = i1; s1 = s0; i1 = i0; s0 = v; i0 = m; }
      else if (v > s1) { s2 = s1; i2 = i1; s1 = v; i1 = m; }
      else if (v > s2) { s2 = v; i2 = m; }
    }
    float e1 = __expf(s1 - s0), e2 = __expf(s2 - s0);
    float inv = 1.f / (1.f + e1 + e2);
    meta[tok0 + tid] = make_float4(inv, e1 * inv, e2 * inv,
                                   __int_as_float(i0 | (i1 << 8) | (i2 << 16)));
  }
}

// ---------------------------------------------------------------------------
// gemm_h: hb = xb @ Wf1b^T  (bf16)
// 256(tok) x 128(d) tile, BK=64, XOR-swizzled LDS layout (global-source
// column swizzle; read chunk (quad+4ks)^(cl&7)) -> conflict-free ds_read_b128.
// grid 512 linear, XCD swizzle: tok-tile = b & 63, dt = b >> 6.
// ---------------------------------------------------------------------------
__global__ __launch_bounds__(256, 2) void gemm_h_kernel(
    const unsigned short* __restrict__ xb, const unsigned short* __restrict__ Wf1b,
    unsigned short* __restrict__ hb) {
  __shared__ __attribute__((aligned(16))) unsigned short As[256 * 64];
  __shared__ __attribute__((aligned(16))) unsigned short Bs[128 * 64];
  const int tid = threadIdx.x;
  const int wave = tid >> 6, lane = tid & 63;
  const int b = blockIdx.x;
  const int tok0 = (b & 63) * 256, d0 = (b >> 6) * 128;
  const int quad = lane >> 4, cl = lane & 15;
  const int wm = wave * 64;   // each wave owns 64 token rows, all 128 d cols
  const int sw = ((lane & 7) ^ (lane >> 3)) * 8;    // staging swizzle (shorts)
  const int cx0 = ((quad) ^ (cl & 7)) * 8;
  const int cx1 = ((quad + 4) ^ (cl & 7)) * 8;

  f32x4 acc[4][8];
#pragma unroll
  for (int i = 0; i < 4; ++i)
#pragma unroll
    for (int j = 0; j < 8; ++j) acc[i][j] = {0.f, 0.f, 0.f, 0.f};

  for (int kt = 0; kt < 16; ++kt) {
    __syncthreads();
#pragma unroll
    for (int i = 0; i < 8; ++i) {   // A: 256 rows x 64 cols = 2048 chunks
      int ch = (wave * 8 + i) * 64 + lane;
      int row = ch >> 3;
      gld16(xb + (size_t)(tok0 + row) * 1024 + kt * 64 + sw, As + ch * 8);
    }
#pragma unroll
    for (int i = 0; i < 4; ++i) {   // B: 128 rows x 64 cols = 1024 chunks
      int ch = (wave * 4 + i) * 64 + lane;
      int row = ch >> 3;
      gld16(Wf1b + (size_t)(d0 + row) * 1024 + kt * 64 + sw, Bs + ch * 8);
    }
    __syncthreads();
#pragma unroll
    for (int ks = 0; ks < 2; ++ks) {
      const int cx = ks ? cx1 : cx0;
      bf16x8 a[4], bb[8];
#pragma unroll
      for (int t = 0; t < 4; ++t)
        a[t] = *(const bf16x8*)(As + (wm + cl + t * 16) * 64 + cx);
#pragma unroll
      for (int t = 0; t < 8; ++t)
        bb[t] = *(const bf16x8*)(Bs + (cl + t * 16) * 64 + cx);
#pragma unroll
      for (int mt = 0; mt < 4; ++mt)
#pragma unroll
        for (int nt = 0; nt < 8; ++nt)
          acc[mt][nt] = __builtin_amdgcn_mfma_f32_16x16x32_bf16(a[mt], bb[nt], acc[mt][nt], 0, 0, 0);
    }
  }

  // epilogue: plain bf16 store (bias + retrieval handled in ln_relu)
#pragma unroll
  for (int mt = 0; mt < 4; ++mt) {
#pragma unroll
    for (int r = 0; r < 4; ++r) {
      int row = tok0 + wm + mt * 16 + quad * 4 + r;
#pragma unroll
      for (int nt = 0; nt < 8; ++nt) {
        int d = d0 + nt * 16 + cl;
        hb[(size_t)row * 1024 + d] = f2bf(acc[mt][nt][r]);
      }
    }
  }
}

// ---------------------------------------------------------------------------
// ln_relu: h = hb + bf + w0*P[i0] + w1*P[i1] + w2*P[i2];
//          out = ReLU(LN(h) * gamma + beta).  One wave per token.
// grid: 4096 blocks x 256
// ---------------------------------------------------------------------------
__global__ __launch_bounds__(256) void ln_relu_kernel(
    const unsigned short* __restrict__ hb, const float* __restrict__ P,
    const float4* __restrict__ meta, const float* __restrict__ bfv,
    const float* __restrict__ gamma, const float* __restrict__ beta,
    float* __restrict__ out) {
  const int tid = threadIdx.x;
  const int wave = tid >> 6, lane = tid & 63;
  const int t = blockIdx.x * 4 + wave;
  const int dbase = lane * 16;

  float4 mv = meta[t];
  int pk = __float_as_int(mv.w);
  const float* P0 = P + (pk & 255) * 1024 + dbase;
  const float* P1 = P + ((pk >> 8) & 255) * 1024 + dbase;
  const float* P2 = P + ((pk >> 16) & 255) * 1024 + dbase;
  const float* bp = bfv + dbase;

  const unsigned short* hp = hb + (size_t)t * 1024 + dbase;
  u16x8 h0 = *(const u16x8*)(hp);
  u16x8 h1 = *(const u16x8*)(hp + 8);
  float f[16];
#pragma unroll
  for (int j = 0; j < 8; ++j) { f[j] = bf2f(h0[j]); f[8 + j] = bf2f(h1[j]); }
#pragma unroll
  for (int j4 = 0; j4 < 4; ++j4) {
    float4 b4 = *(const float4*)(bp + j4 * 4);
    float4 p0 = *(const float4*)(P0 + j4 * 4);
    float4 p1 = *(const float4*)(P1 + j4 * 4);
    float4 p2 = *(const float4*)(P2 + j4 * 4);
    f[j4 * 4 + 0] += b4.x + mv.x * p0.x + mv.y * p1.x + mv.z * p2.x;
    f[j4 * 4 + 1] += b4.y + mv.x * p0.y + mv.y * p1.y + mv.z * p2.y;
    f[j4 * 4 + 2] += b4.z + mv.x * p0.z + mv.y * p1.z + mv.z * p2.z;
    f[j4 * 4 + 3] += b4.w + mv.x * p0.w + mv.y * p1.w + mv.z * p2.w;
  }
  float s = 0.f, q = 0.f;
#pragma unroll
  for (int j = 0; j < 16; ++j) { s += f[j]; q += f[j] * f[j]; }
#pragma unroll
  for (int off = 32; off; off >>= 1) {
    s += __shfl_xor(s, off);
    q += __shfl_xor(q, off);
  }
  float mean = s * (1.f / 1024.f);
  float var = q * (1.f / 1024.f) - mean * mean;
  float rs = rsqrtf(var + 1e-5f);
  float* op = out + (size_t)t * 1024 + dbase;
#pragma unroll
  for (int j4 = 0; j4 < 4; ++j4) {
    float4 g4 = *(const float4*)(gamma + dbase + j4 * 4);
    float4 e4 = *(const float4*)(beta + dbase + j4 * 4);
    float4 v;
    v.x = fmaxf((f[j4 * 4 + 0] - mean) * rs * g4.x + e4.x, 0.f);
    v.y = fmaxf((f[j4 * 4 + 1] - mean) * rs * g4.y + e4.y, 0.f);
    v.z = fmaxf((f[j4 * 4 + 2] - mean) * rs * g4.z + e4.z, 0.f);
    v.w = fmaxf((f[j4 * 4 + 3] - mean) * rs * g4.w + e4.w, 0.f);
    *(float4*)(op + j4 * 4) = v;
  }
}

// ---------------------------------------------------------------------------
extern "C" void kernel_launch(void* const* d_in, const int* in_sizes, int n_in,
                              void* d_out, int out_size, void* d_ws, size_t ws_size,
                              hipStream_t stream) {
  const float* x     = (const float*)d_in[0];
  const float* memv  = (const float*)d_in[1];
  const float* Wq    = (const float*)d_in[2];
  const float* bq    = (const float*)d_in[3];
  const float* Wf    = (const float*)d_in[4];
  const float* bfv   = (const float*)d_in[5];
  const float* gamma = (const float*)d_in[6];
  const float* beta  = (const float*)d_in[7];
  float* out = (float*)d_out;
  char* ws = (char*)d_ws;

  unsigned short* Wf1b   = (unsigned short*)(ws);              // 2 MB
  unsigned short* Wmb    = (unsigned short*)(ws + 2097152);    // 128 KB
  float*          P      = (float*)(ws + 2228224);             // 256 KB
  float*          sc     = (float*)(ws + 2490368);             // 256 B
  float4*         meta   = (float4*)(ws + 2490624);            // 256 KB
  float*          Wf2T   = (float*)(ws + 2752768);             // 4 MB
  float*          partWm = (float*)(ws + 6947072);             // 2 MB
  float*          partP  = (float*)(ws + 9044224);             // 2 MB
  unsigned short* xb     = (unsigned short*)(ws + 11141376);   // 32 MB
  unsigned short* hb     = (unsigned short*)(ws + 44695808);   // 32 MB
  // total ws usage: 78,250,240 bytes

  hipLaunchKernelGGL(prep_a_kernel, dim3(2369), dim3(256), 0, stream,
                     x, xb, Wf, Wf2T, Wf1b, bq, memv, sc);
  hipLaunchKernelGGL(prep_b_kernel, dim3(256), dim3(256), 0, stream,
                     memv, Wq, Wf2T, partWm, partP);
  hipLaunchKernelGGL(prep_c_kernel, dim3(512), dim3(256), 0, stream,
                     partWm, partP, Wmb, P);
  hipLaunchKernelGGL(sim_topk_kernel, dim3(256), dim3(256), 0, stream,
                     xb, Wmb, sc, meta);
  hipLaunchKernelGGL(gemm_h_kernel, dim3(512), dim3(256), 0, stream,
                     xb, Wf1b, hb);
  hipLaunchKernelGGL(ln_relu_kernel, dim3(4096), dim3(256), 0, stream,
                     hb, P, meta, bfv, gamma, beta, out);
}

// Round 7
// 262.310 us; speedup vs baseline: 1.0069x; 1.0069x over previous
//
#include <hip/hip_runtime.h>

#define DCH 1024
#define MSLOT 64
#define NTOK 16384

typedef __bf16 bf16x8 __attribute__((ext_vector_type(8)));
typedef float f32x4 __attribute__((ext_vector_type(4)));
typedef unsigned short u16x8 __attribute__((ext_vector_type(8)));
typedef unsigned short u16x4 __attribute__((ext_vector_type(4)));

__device__ __forceinline__ unsigned short f2bf(float f) {
  unsigned u = __float_as_uint(f);
  u += 0x7fffu + ((u >> 16) & 1u);
  return (unsigned short)(u >> 16);
}
__device__ __forceinline__ float bf2f(unsigned short s) {
  return __uint_as_float(((unsigned)s) << 16);
}

__device__ __forceinline__ void gld16(const void* g, void* l) {
  __builtin_amdgcn_global_load_lds((const __attribute__((address_space(1))) void*)g,
                                   (__attribute__((address_space(3))) void*)l, 16, 0, 0);
}

// ---------------------------------------------------------------------------
// xconv: x (f32) -> xb (bf16). Pure streaming, grid-stride, 8 float4/thread,
// 4 independent loads in flight. 2048 blocks x 256.
// (Split out of prep_a: R4-R6 showed prep_a pinned at 46us regardless of
//  x-conv structure -- the fused small blocks straggled behind these 2048.)
// ---------------------------------------------------------------------------
__global__ __launch_bounds__(256) void xconv_kernel(
    const float* __restrict__ x, unsigned short* __restrict__ xb) {
  const int base = blockIdx.x * 256 + threadIdx.x;   // float4 index
  const int stride = 2048 * 256;
#pragma unroll
  for (int half = 0; half < 2; ++half) {
    float4 v[4];
#pragma unroll
    for (int j = 0; j < 4; ++j)
      v[j] = *(const float4*)(x + (size_t)(base + (half * 4 + j) * stride) * 4);
#pragma unroll
    for (int j = 0; j < 4; ++j) {
      u16x4 o = {f2bf(v[j].x), f2bf(v[j].y), f2bf(v[j].z), f2bf(v[j].w)};
      *(u16x4*)(xb + (size_t)(base + (half * 4 + j) * stride) * 4) = o;
    }
  }
}

// ---------------------------------------------------------------------------
// prep_w: weight-side prep, runs on an empty machine (no straggler queue).
//   b in [0,256)   : Wf2 transpose -> Wf2T[c][d] (fp32), 64x64 tiles,
//                    float4 on both global sides
//   b in [256,320) : Wf1 -> bf16
//   b == 320       : sc[m] = bq . memory[m], per-wave coalesced + shuffle
// ---------------------------------------------------------------------------
__global__ __launch_bounds__(256) void prep_w_kernel(
    const float* __restrict__ Wf, float* __restrict__ Wf2T,
    unsigned short* __restrict__ Wf1b,
    const float* __restrict__ bq, const float* __restrict__ memv,
    float* __restrict__ sc) {
  __shared__ float tile[64][65];
  const int b = blockIdx.x, tid = threadIdx.x;

  if (b < 256) {
    const int c0 = (b & 15) * 64, d0 = (b >> 4) * 64;
    const int r16 = tid >> 4, c4 = (tid & 15) * 4;
#pragma unroll
    for (int k = 0; k < 4; ++k) {
      int row = r16 + k * 16;    // d-row within tile
      float4 v = *(const float4*)(Wf + (size_t)(d0 + row) * 2048 + 1024 + c0 + c4);
      tile[row][c4 + 0] = v.x; tile[row][c4 + 1] = v.y;
      tile[row][c4 + 2] = v.z; tile[row][c4 + 3] = v.w;
    }
    __syncthreads();
#pragma unroll
    for (int k = 0; k < 4; ++k) {
      int cc = r16 + k * 16;     // c-row within tile
      float4 v = {tile[c4 + 0][cc], tile[c4 + 1][cc],
                  tile[c4 + 2][cc], tile[c4 + 3][cc]};
      *(float4*)(Wf2T + (size_t)(c0 + cc) * 1024 + d0 + c4) = v;
    }
  } else if (b < 320) {
    const int j = b - 256;   // Wf1 -> bf16, 64 blocks, 4096 float4 each
#pragma unroll
    for (int i = 0; i < 16; ++i) {
      int f4 = j * 4096 + i * 256 + tid;
      int row = f4 >> 8, c4 = (f4 & 255) * 4;
      float4 v = *(const float4*)(Wf + (size_t)row * 2048 + c4);
      u16x4 o = {f2bf(v.x), f2bf(v.y), f2bf(v.z), f2bf(v.w)};
      *(u16x4*)(Wf1b + row * 1024 + c4) = o;
    }
  } else {
    // sc[m] = bq . memory[m]; wave w handles m = w*16..w*16+15,
    // lane-coalesced float4 reads + wave shuffle-reduce per m.
    const int wv = tid >> 6, lane = tid & 63;
    const float* bp = bq + lane * 16;
#pragma unroll 2
    for (int i = 0; i < 16; ++i) {
      int m = wv * 16 + i;
      const float* mp = memv + m * 1024 + lane * 16;
      float s = 0.f;
#pragma unroll
      for (int j4 = 0; j4 < 4; ++j4) {
        float4 a = *(const float4*)(mp + j4 * 4);
        float4 c = *(const float4*)(bp + j4 * 4);
        s += a.x * c.x + a.y * c.y + a.z * c.z + a.w * c.w;
      }
#pragma unroll
      for (int off = 32; off; off >>= 1) s += __shfl_xor(s, off);
      if (lane == 0) sc[m] = s;
    }
  }
}

// ---------------------------------------------------------------------------
// prep_b: split-K partial GEMMs (M=64, N=1024, K=1024, fp32 VALU).
// ---------------------------------------------------------------------------
__global__ __launch_bounds__(256) void prep_b_kernel(
    const float* __restrict__ memv, const float* __restrict__ Wq,
    const float* __restrict__ Wf2T,
    float* __restrict__ partWm, float* __restrict__ partP) {
  int b = blockIdx.x;
  const int tid = threadIdx.x;
  const int which = b >> 7;
  b &= 127;
  const int kc = b & 7, dt = (b >> 3) & 3, mg = b >> 5;
  const float* B = which ? Wf2T : Wq;
  float* outp = which ? partP : partWm;
  const int d = dt * 256 + tid;
  const int e0 = kc * 128;
  const int m0 = mg * 16;

  float acc[16];
#pragma unroll
  for (int m = 0; m < 16; ++m) acc[m] = 0.f;

  const float* bp = B + (size_t)e0 * 1024 + d;
  const float* mp = memv + m0 * 1024 + e0;
#pragma unroll 4
  for (int e = 0; e < 128; ++e) {
    float wv = bp[(size_t)e * 1024];
#pragma unroll
    for (int m = 0; m < 16; ++m) acc[m] += mp[m * 1024 + e] * wv;
  }
  float* op = outp + ((size_t)kc * 64 + m0) * 1024 + d;
#pragma unroll
  for (int m = 0; m < 16; ++m) op[m * 1024] = acc[m];
}

// ---------------------------------------------------------------------------
// prep_c: reduce 8 partials. idx < 65536 -> Wmb (bf16); else -> P (fp32)
// ---------------------------------------------------------------------------
__global__ __launch_bounds__(256) void prep_c_kernel(
    const float* __restrict__ partWm, const float* __restrict__ partP,
    unsigned short* __restrict__ Wmb, float* __restrict__ P) {
  int idx = blockIdx.x * 256 + threadIdx.x;
  if (idx < 65536) {
    float s = 0.f;
#pragma unroll
    for (int k = 0; k < 8; ++k) s += partWm[k * 65536 + idx];
    Wmb[idx] = f2bf(s);
  } else {
    idx -= 65536;
    float s = 0.f;
#pragma unroll
    for (int k = 0; k < 8; ++k) s += partP[k * 65536 + idx];
    P[idx] = s;
  }
}

// ---------------------------------------------------------------------------
// sim_topk: sim = xb @ Wmb^T + sc  (64 tok x 64 m per block), then per-token
// top-3 + softmax -> meta.  XOR-swizzled LDS (see gemm_h comment).
// grid: 256 blocks x 256
// ---------------------------------------------------------------------------
__global__ __launch_bounds__(256) void sim_topk_kernel(
    const unsigned short* __restrict__ xb, const unsigned short* __restrict__ Wmb,
    const float* __restrict__ sc, float4* __restrict__ meta) {
  __shared__ __attribute__((aligned(16))) unsigned short As[64 * 64];
  __shared__ __attribute__((aligned(16))) unsigned short Bs[64 * 64];
  __shared__ float sim_s[64 * 65];
  const int tid = threadIdx.x;
  const int wave = tid >> 6, lane = tid & 63;
  const int tok0 = blockIdx.x * 64;
  const int quad = lane >> 4, cl = lane & 15;
  const int sw = ((lane & 7) ^ (lane >> 3)) * 8;    // staging swizzle (shorts)
  const int cx0 = ((quad) ^ (cl & 7)) * 8;          // read swizzle ks=0
  const int cx1 = ((quad + 4) ^ (cl & 7)) * 8;      // read swizzle ks=1

  f32x4 acc[4];
#pragma unroll
  for (int j = 0; j < 4; ++j) acc[j] = {0.f, 0.f, 0.f, 0.f};

  for (int kt = 0; kt < 16; ++kt) {
    __syncthreads();
#pragma unroll
    for (int i = 0; i < 2; ++i) {
      int ch = (wave * 2 + i) * 64 + lane;
      int row = ch >> 3;
      gld16(xb + (size_t)(tok0 + row) * 1024 + kt * 64 + sw, As + ch * 8);
      gld16(Wmb + row * 1024 + kt * 64 + sw, Bs + ch * 8);
    }
    __syncthreads();
#pragma unroll
    for (int ks = 0; ks < 2; ++ks) {
      const int cx = ks ? cx1 : cx0;
      bf16x8 a = *(const bf16x8*)(As + (wave * 16 + cl) * 64 + cx);
#pragma unroll
      for (int nt = 0; nt < 4; ++nt) {
        bf16x8 bb = *(const bf16x8*)(Bs + (cl + nt * 16) * 64 + cx);
        acc[nt] = __builtin_amdgcn_mfma_f32_16x16x32_bf16(a, bb, acc[nt], 0, 0, 0);
      }
    }
  }
#pragma unroll
  for (int nt = 0; nt < 4; ++nt)
#pragma unroll
    for (int r = 0; r < 4; ++r) {
      int lt = wave * 16 + quad * 4 + r;
      int mc = nt * 16 + cl;
      sim_s[lt * 65 + mc] = acc[nt][r] + sc[mc];
    }
  __syncthreads();
  if (tid < 64) {
    const float* sp = sim_s + tid * 65;
    float s0 = -1e30f, s1 = -1e30f, s2 = -1e30f;
    int i0 = 0, i1 = 0, i2 = 0;
    for (int m = 0; m < 64; ++m) {
      float v = sp[m];
      if (v > s0) { s2 = s1; i2 = i1; s1 = s0; i1 = i0; s0 = v; i0 = m; }
      else if (v > s1) { s2 = s1; i2 = i1; s1 = v; i1 = m; }
      else if (v > s2) { s2 = v; i2 = m; }
    }
    float e1 = __expf(s1 - s0), e2 = __expf(s2 - s0);
    float inv = 1.f / (1.f + e1 + e2);
    meta[tok0 + tid] = make_float4(inv, e1 * inv, e2 * inv,
                                   __int_as_float(i0 | (i1 << 8) | (i2 << 16)));
  }
}

// ---------------------------------------------------------------------------
// gemm_h: hb = xb @ Wf1b^T  (bf16)
// 256(tok) x 128(d) tile, BK=64, XOR-swizzled LDS layout (global-source
// column swizzle; read chunk (quad+4ks)^(cl&7)) -> conflict-free ds_read_b128.
// grid 512 linear, XCD swizzle: tok-tile = b & 63, dt = b >> 6.
// ---------------------------------------------------------------------------
__global__ __launch_bounds__(256, 2) void gemm_h_kernel(
    const unsigned short* __restrict__ xb, const unsigned short* __restrict__ Wf1b,
    unsigned short* __restrict__ hb) {
  __shared__ __attribute__((aligned(16))) unsigned short As[256 * 64];
  __shared__ __attribute__((aligned(16))) unsigned short Bs[128 * 64];
  const int tid = threadIdx.x;
  const int wave = tid >> 6, lane = tid & 63;
  const int b = blockIdx.x;
  const int tok0 = (b & 63) * 256, d0 = (b >> 6) * 128;
  const int quad = lane >> 4, cl = lane & 15;
  const int wm = wave * 64;   // each wave owns 64 token rows, all 128 d cols
  const int sw = ((lane & 7) ^ (lane >> 3)) * 8;    // staging swizzle (shorts)
  const int cx0 = ((quad) ^ (cl & 7)) * 8;
  const int cx1 = ((quad + 4) ^ (cl & 7)) * 8;

  f32x4 acc[4][8];
#pragma unroll
  for (int i = 0; i < 4; ++i)
#pragma unroll
    for (int j = 0; j < 8; ++j) acc[i][j] = {0.f, 0.f, 0.f, 0.f};

  for (int kt = 0; kt < 16; ++kt) {
    __syncthreads();
#pragma unroll
    for (int i = 0; i < 8; ++i) {   // A: 256 rows x 64 cols = 2048 chunks
      int ch = (wave * 8 + i) * 64 + lane;
      int row = ch >> 3;
      gld16(xb + (size_t)(tok0 + row) * 1024 + kt * 64 + sw, As + ch * 8);
    }
#pragma unroll
    for (int i = 0; i < 4; ++i) {   // B: 128 rows x 64 cols = 1024 chunks
      int ch = (wave * 4 + i) * 64 + lane;
      int row = ch >> 3;
      gld16(Wf1b + (size_t)(d0 + row) * 1024 + kt * 64 + sw, Bs + ch * 8);
    }
    __syncthreads();
#pragma unroll
    for (int ks = 0; ks < 2; ++ks) {
      const int cx = ks ? cx1 : cx0;
      bf16x8 a[4], bb[8];
#pragma unroll
      for (int t = 0; t < 4; ++t)
        a[t] = *(const bf16x8*)(As + (wm + cl + t * 16) * 64 + cx);
#pragma unroll
      for (int t = 0; t < 8; ++t)
        bb[t] = *(const bf16x8*)(Bs + (cl + t * 16) * 64 + cx);
#pragma unroll
      for (int mt = 0; mt < 4; ++mt)
#pragma unroll
        for (int nt = 0; nt < 8; ++nt)
          acc[mt][nt] = __builtin_amdgcn_mfma_f32_16x16x32_bf16(a[mt], bb[nt], acc[mt][nt], 0, 0, 0);
    }
  }

  // epilogue: plain bf16 store (bias + retrieval handled in ln_relu)
#pragma unroll
  for (int mt = 0; mt < 4; ++mt) {
#pragma unroll
    for (int r = 0; r < 4; ++r) {
      int row = tok0 + wm + mt * 16 + quad * 4 + r;
#pragma unroll
      for (int nt = 0; nt < 8; ++nt) {
        int d = d0 + nt * 16 + cl;
        hb[(size_t)row * 1024 + d] = f2bf(acc[mt][nt][r]);
      }
    }
  }
}

// ---------------------------------------------------------------------------
// ln_relu: h = hb + bf + w0*P[i0] + w1*P[i1] + w2*P[i2];
//          out = ReLU(LN(h) * gamma + beta).  One wave per token.
// grid: 4096 blocks x 256
// ---------------------------------------------------------------------------
__global__ __launch_bounds__(256) void ln_relu_kernel(
    const unsigned short* __restrict__ hb, const float* __restrict__ P,
    const float4* __restrict__ meta, const float* __restrict__ bfv,
    const float* __restrict__ gamma, const float* __restrict__ beta,
    float* __restrict__ out) {
  const int tid = threadIdx.x;
  const int wave = tid >> 6, lane = tid & 63;
  const int t = blockIdx.x * 4 + wave;
  const int dbase = lane * 16;

  float4 mv = meta[t];
  int pk = __float_as_int(mv.w);
  const float* P0 = P + (pk & 255) * 1024 + dbase;
  const float* P1 = P + ((pk >> 8) & 255) * 1024 + dbase;
  const float* P2 = P + ((pk >> 16) & 255) * 1024 + dbase;
  const float* bp = bfv + dbase;

  const unsigned short* hp = hb + (size_t)t * 1024 + dbase;
  u16x8 h0 = *(const u16x8*)(hp);
  u16x8 h1 = *(const u16x8*)(hp + 8);
  float f[16];
#pragma unroll
  for (int j = 0; j < 8; ++j) { f[j] = bf2f(h0[j]); f[8 + j] = bf2f(h1[j]); }
#pragma unroll
  for (int j4 = 0; j4 < 4; ++j4) {
    float4 b4 = *(const float4*)(bp + j4 * 4);
    float4 p0 = *(const float4*)(P0 + j4 * 4);
    float4 p1 = *(const float4*)(P1 + j4 * 4);
    float4 p2 = *(const float4*)(P2 + j4 * 4);
    f[j4 * 4 + 0] += b4.x + mv.x * p0.x + mv.y * p1.x + mv.z * p2.x;
    f[j4 * 4 + 1] += b4.y + mv.x * p0.y + mv.y * p1.y + mv.z * p2.y;
    f[j4 * 4 + 2] += b4.z + mv.x * p0.z + mv.y * p1.z + mv.z * p2.z;
    f[j4 * 4 + 3] += b4.w + mv.x * p0.w + mv.y * p1.w + mv.z * p2.w;
  }
  float s = 0.f, q = 0.f;
#pragma unroll
  for (int j = 0; j < 16; ++j) { s += f[j]; q += f[j] * f[j]; }
#pragma unroll
  for (int off = 32; off; off >>= 1) {
    s += __shfl_xor(s, off);
    q += __shfl_xor(q, off);
  }
  float mean = s * (1.f / 1024.f);
  float var = q * (1.f / 1024.f) - mean * mean;
  float rs = rsqrtf(var + 1e-5f);
  float* op = out + (size_t)t * 1024 + dbase;
#pragma unroll
  for (int j4 = 0; j4 < 4; ++j4) {
    float4 g4 = *(const float4*)(gamma + dbase + j4 * 4);
    float4 e4 = *(const float4*)(beta + dbase + j4 * 4);
    float4 v;
    v.x = fmaxf((f[j4 * 4 + 0] - mean) * rs * g4.x + e4.x, 0.f);
    v.y = fmaxf((f[j4 * 4 + 1] - mean) * rs * g4.y + e4.y, 0.f);
    v.z = fmaxf((f[j4 * 4 + 2] - mean) * rs * g4.z + e4.z, 0.f);
    v.w = fmaxf((f[j4 * 4 + 3] - mean) * rs * g4.w + e4.w, 0.f);
    *(float4*)(op + j4 * 4) = v;
  }
}

// ---------------------------------------------------------------------------
extern "C" void kernel_launch(void* const* d_in, const int* in_sizes, int n_in,
                              void* d_out, int out_size, void* d_ws, size_t ws_size,
                              hipStream_t stream) {
  const float* x     = (const float*)d_in[0];
  const float* memv  = (const float*)d_in[1];
  const float* Wq    = (const float*)d_in[2];
  const float* bq    = (const float*)d_in[3];
  const float* Wf    = (const float*)d_in[4];
  const float* bfv   = (const float*)d_in[5];
  const float* gamma = (const float*)d_in[6];
  const float* beta  = (const float*)d_in[7];
  float* out = (float*)d_out;
  char* ws = (char*)d_ws;

  unsigned short* Wf1b   = (unsigned short*)(ws);              // 2 MB
  unsigned short* Wmb    = (unsigned short*)(ws + 2097152);    // 128 KB
  float*          P      = (float*)(ws + 2228224);             // 256 KB
  float*          sc     = (float*)(ws + 2490368);             // 256 B
  float4*         meta   = (float4*)(ws + 2490624);            // 256 KB
  float*          Wf2T   = (float*)(ws + 2752768);             // 4 MB
  float*          partWm = (float*)(ws + 6947072);             // 2 MB
  float*          partP  = (float*)(ws + 9044224);             // 2 MB
  unsigned short* xb     = (unsigned short*)(ws + 11141376);   // 32 MB
  unsigned short* hb     = (unsigned short*)(ws + 44695808);   // 32 MB
  // total ws usage: 78,250,240 bytes

  hipLaunchKernelGGL(prep_w_kernel, dim3(321), dim3(256), 0, stream,
                     Wf, Wf2T, Wf1b, bq, memv, sc);
  hipLaunchKernelGGL(prep_b_kernel, dim3(256), dim3(256), 0, stream,
                     memv, Wq, Wf2T, partWm, partP);
  hipLaunchKernelGGL(prep_c_kernel, dim3(512), dim3(256), 0, stream,
                     partWm, partP, Wmb, P);
  hipLaunchKernelGGL(xconv_kernel, dim3(2048), dim3(256), 0, stream, x, xb);
  hipLaunchKernelGGL(sim_topk_kernel, dim3(256), dim3(256), 0, stream,
                     xb, Wmb, sc, meta);
  hipLaunchKernelGGL(gemm_h_kernel, dim3(512), dim3(256), 0, stream,
                     xb, Wf1b, hb);
  hipLaunchKernelGGL(ln_relu_kernel, dim3(4096), dim3(256), 0, stream,
                     hb, P, meta, bfv, gamma, beta, out);
}